// Round 1
// baseline (9921.495 us; speedup 1.0000x reference)
//
#include <hip/hip_runtime.h>

// Seq2Seq LSTM H=128: enc 8192 + dec 4096 strictly sequential steps.
// Main block on one CU, 512 threads (8 waves). ONE barrier per step.
// Kernel body identical to R7/R8 (9.1 ms).
//
// R9 changes (instrument + cleanup; main block untouched):
//  * HEATERS REMOVED (grid 256 -> 2). rocprof showed heater-ACTIVE
//    dispatches (first of each pass, wsflag fresh) run 39.9 ms / 16 MB
//    fetch vs 9.14 ms / 315 KB when heaters see stale MAGIC and exit.
//    Heaters actively downclock the chip (memory-stall signature ->
//    DPM drops core clock); in timed runs they were inert. Remove.
//  * CLOCK PROBER (block 1, 1 wave): counts dependent v_fma chains
//    (~4 cyc each, clock-invariant) against s_memrealtime (100 MHz)
//    while the main block runs; polls wsflag only every ~13 us (one
//    quiet poller, no governor perturbation). Encodes measured core
//    MHz as a duration tail of MHz/2 us -> read from the FIRST
//    dispatch of each rocprof pass: MHz = 2*(dur_first - dur_steady).
//    Re-poisoned iterations degenerate to a 50 us tail, keeping the
//    timed headline clean.

#define H      128
#define ENC_T  8192
#define DEC_T  4096
#define NT     512
#define NBLK   2
#define MAGIC  0xC0FFEEu
#define PSLICE 648          // floats per slice stride; idx = 5u+g <= 638

typedef float v2f __attribute__((ext_vector_type(2)));

__device__ __forceinline__ v2f pk_fma(v2f a, v2f b, v2f c) {
    v2f d;
    asm("v_pk_fma_f32 %0, %1, %2, %3" : "=v"(d) : "v"(a), "v"(b), "v"(c));
    return d;
}
__device__ __forceinline__ float sigm(float x) {
    return __builtin_amdgcn_rcpf(1.0f + __expf(-x));   // exact at +-inf
}
__device__ __forceinline__ float tanhfast(float x) {
    return 1.0f - 2.0f * __builtin_amdgcn_rcpf(1.0f + __expf(2.0f * x));
}
__device__ __forceinline__ float rdlane(float v, int l) {
    return __int_as_float(__builtin_amdgcn_readlane(__float_as_int(v), l));
}
template <int CTRL>
__device__ __forceinline__ float qperm(float v) {      // DPP quad_perm, VALU-speed
    return __int_as_float(
        __builtin_amdgcn_mov_dpp(__float_as_int(v), CTRL, 0xf, 0xf, true));
}
__device__ __forceinline__ unsigned long long memreal() {   // 100 MHz RTC
    unsigned long long v;
    asm volatile("s_memrealtime %0\n\ts_waitcnt lgkmcnt(0)" : "=s"(v));
    return v;
}

__global__ __launch_bounds__(NT, 2)
void seq2seq_lstm(const float* __restrict__ input_seq,
                  const float* __restrict__ enc_Wih,
                  const float* __restrict__ enc_Whh,
                  const float* __restrict__ enc_bih,
                  const float* __restrict__ enc_bhh,
                  const float* __restrict__ dec_Wih,
                  const float* __restrict__ dec_Whh,
                  const float* __restrict__ dec_bih,
                  const float* __restrict__ dec_bhh,
                  const float* __restrict__ fc_W,
                  const float* __restrict__ fc_b,
                  float* __restrict__ out,
                  unsigned* __restrict__ wsflag)
{
    // ---- clock prober: one quiet wave on its own CU ----
    if (blockIdx.x != 0) {
        if (threadIdx.x != 0) return;
        const unsigned long long r0 = memreal();
        unsigned long long loops = 0;
        float z = 1.0000001f;
        while (loops < 4000ull) {     // cap ~54 ms @2.4 GHz; normal exit via MAGIC
            if (__hip_atomic_load(wsflag, __ATOMIC_RELAXED,
                                  __HIP_MEMORY_SCOPE_AGENT) == MAGIC)
                break;
            // 8192 dependent v_fma ~= 32768 core cycles (clock-invariant)
#pragma unroll 32
            for (int k = 0; k < 8192; ++k)
                z = __builtin_fmaf(z, 0.99999988f, 1.0e-12f);
            ++loops;
        }
        asm volatile("" :: "v"(z));   // keep chain live (no DCE)
        const unsigned long long r1 = memreal();
        const unsigned long long ticks = r1 - r0;           // 100 MHz ticks
        // core_cycles ~= loops * 8192 * 4 ; MHz = cycles*100/ticks
        unsigned long long mhz = ticks ? (loops * 8192ull * 400ull) / ticks : 0;
        if (mhz < 100)  mhz = 100;
        if (mhz > 4000) mhz = 4000;
        const unsigned long long tgt = mhz * 50ull;         // tail = MHz/2 us
        while (memreal() - r1 < tgt) {}
        return;
    }

    // ---- main block (identical to R7/R8) ----
    __shared__ __align__(16) float xin[ENC_T];          // 32 KB
    __shared__ __align__(16) float hbuf[2][H];          // h history (off-path)
    __shared__ __align__(16) float part[2][8 * PSLICE]; // dbl-buffered partials

    const int t    = threadIdx.x;      // 0..511
    const int lane = t & 63;
    const int wv   = t >> 6;           // wave 0..7, j-slice [16wv,16wv+16)
    const int jb   = 16 * wv;
    const int qq   = lane >> 2;        // reduce role: unit-in-slice 0..15
    const int g    = lane & 3;         // gate 0=i 1=f 2=g 3=o
    const int myu  = jb + qq;          // my unit (global)
    const int myrow = g * H + myu;     // my gate row
    const int prd  = 5 * myu + g;      // partial read idx within a slice
    const int pwb  = wv * PSLICE + 5 * lane;   // partial write base

    {   // stage input sequence
        const float4* s = (const float4*)input_seq;
        float4* d = (float4*)xin;
        for (int i = t; i < ENC_T / 4; i += NT) d[i] = s[i];
    }

    // matvec weights as j-pairs: w2[s][jj] = Whh[(64s+lane)][jb+2jj, jb+2jj+1]
    v2f w2[8][8];
#pragma unroll
    for (int s = 0; s < 8; ++s) {
        const v2f* Wr = (const v2f*)(enc_Whh + (64 * s + lane) * H + jb);
#pragma unroll
        for (int jj = 0; jj < 8; ++jj) w2[s][jj] = Wr[jj];
    }
    float bias_r = enc_bih[myrow] + enc_bhh[myrow];
    float wih_r  = enc_Wih[myrow];

    float cst = 0.f;      // cell state of unit myu (replicated per quad)
    float hn  = 0.f;      // h of unit myu (replicated per quad)
    __syncthreads();

    // h[jb+2jj+c] lives in quad 2jj+c of this wave -> g==3 lane 8jj+4c+3
#define MATVEC(PB)                                                          \
    {                                                                       \
        v2f acc2[8];                                                        \
        _Pragma("unroll") for (int s = 0; s < 8; ++s)                       \
            acc2[s] = (v2f){0.f, 0.f};                                      \
        _Pragma("unroll") for (int jj = 0; jj < 8; ++jj) {                  \
            const float se = rdlane(hn, 8 * jj + 3);                        \
            const float so = rdlane(hn, 8 * jj + 7);                        \
            const v2f hp = {se, so};                                        \
            _Pragma("unroll") for (int s = 0; s < 8; ++s)                   \
                acc2[s] = pk_fma(w2[s][jj], hp, acc2[s]);                   \
        }                                                                   \
        /* row 64s+lane -> idx 5*lane + 320*(s&1) + (s>>1), stride-5 */     \
        float* pb_ = &part[PB][pwb];                                        \
        pb_[0]   = acc2[0].x + acc2[0].y; pb_[320] = acc2[1].x + acc2[1].y; \
        pb_[1]   = acc2[2].x + acc2[2].y; pb_[321] = acc2[3].x + acc2[3].y; \
        pb_[2]   = acc2[4].x + acc2[4].y; pb_[322] = acc2[5].x + acc2[5].y; \
        pb_[3]   = acc2[6].x + acc2[6].y; pb_[323] = acc2[7].x + acc2[7].y; \
    }

#define REDUCE_UPDATE(PB, ABASE)                                            \
    {                                                                       \
        float a = (ABASE);                                                  \
        _Pragma("unroll") for (int s = 0; s < 8; ++s)                       \
            a += part[PB][s * PSLICE + prd];                                \
        const float v = (g == 2) ? tanhfast(a) : sigm(a);                   \
        const float vi = qperm<0x00>(v);   /* quad lane 0 */                \
        const float vf = qperm<0x55>(v);   /* quad lane 1 */                \
        const float vg = qperm<0xAA>(v);   /* quad lane 2 */                \
        const float vo = qperm<0xFF>(v);   /* quad lane 3 */                \
        cst = fmaf(vf, cst, vi * vg);                                       \
        hn  = vo * tanhfast(cst);                                           \
        if (g == 3) hbuf[PB][myu] = hn;                                     \
    }

    // ---------------- encoder: 8192 steps, ONE barrier each ----------------
    for (int st = 0; st < ENC_T; ++st) {
        const int pb = st & 1;
        MATVEC(pb);
        const float x = xin[st];
        __syncthreads();
        REDUCE_UPDATE(pb, fmaf(wih_r, x, bias_r));
    }

    // ---------------- decoder setup: fold fc into Whh ----------------
    const float fcb = fc_b[0];
    const float fwl = fc_W[lane];
    const float fwh = fc_W[64 + lane];
#pragma unroll
    for (int s = 0; s < 8; ++s) {
        const int r = 64 * s + lane;
        const float vi = dec_Wih[r];
        const v2f vip = {vi, vi};
        const v2f* Wr = (const v2f*)(dec_Whh + r * H + jb);
        const v2f* Fr = (const v2f*)(fc_W + jb);
#pragma unroll
        for (int jj = 0; jj < 8; ++jj)
            w2[s][jj] = pk_fma(vip, Fr[jj], Wr[jj]);   // W' = Whh + wih (x) fcW
    }
    wih_r  = dec_Wih[myrow];
    bias_r = dec_bih[myrow] + dec_bhh[myrow] + wih_r * fcb;
    __syncthreads();                       // h_enc visible in hbuf[1]
    float q0;
    {
        float p = fmaf(fwl, hbuf[1][lane], fwh * hbuf[1][64 + lane]);
        p += qperm<0xB1>(p);               // xor 1
        p += qperm<0x4E>(p);               // xor 2
#pragma unroll
        for (int m = 32; m >= 4; m >>= 1) p += __shfl_xor(p, m, 64);
        q0 = p + fcb;
    }
    float cb = bias_r - wih_r * q0;        // step-0 correction (y0 = 0)

    // ---------------- decoder: 4096 steps ----------------
    for (int st = 0; st < DEC_T; ++st) {
        const int pb = st & 1;
        MATVEC(pb);
        if (wv == 7 && st >= 2) {          // out[st-2] from 2-step-stale hbuf
            float p = fmaf(fwl, hbuf[pb][lane], fwh * hbuf[pb][64 + lane]);
            p += qperm<0xB1>(p);
            p += qperm<0x4E>(p);
#pragma unroll
            for (int m = 32; m >= 4; m >>= 1) p += __shfl_xor(p, m, 64);
            if (lane == 0) out[st - 2] = p + fcb;
        }
        __syncthreads();
        REDUCE_UPDATE(pb, cb);
        cb = bias_r;
    }

    // tail outputs for steps DEC_T-2 (hbuf[0]) and DEC_T-1 (hbuf[1])
    __syncthreads();
    if (wv == 7) {
        float p0 = fmaf(fwl, hbuf[0][lane], fwh * hbuf[0][64 + lane]);
        float p1 = fmaf(fwl, hbuf[1][lane], fwh * hbuf[1][64 + lane]);
#pragma unroll
        for (int m = 32; m >= 1; m >>= 1) {
            p0 += __shfl_xor(p0, m, 64);
            p1 += __shfl_xor(p1, m, 64);
        }
        if (lane == 0) {
            out[DEC_T - 2] = p0 + fcb;
            out[DEC_T - 1] = p1 + fcb;
        }
    }
    if (t == 0)
        __hip_atomic_store(wsflag, MAGIC, __ATOMIC_RELEASE, __HIP_MEMORY_SCOPE_AGENT);
}

extern "C" void kernel_launch(void* const* d_in, const int* in_sizes, int n_in,
                              void* d_out, int out_size, void* d_ws, size_t ws_size,
                              hipStream_t stream)
{
    (void)in_sizes; (void)n_in; (void)ws_size; (void)out_size;
    seq2seq_lstm<<<NBLK, NT, 0, stream>>>(
        (const float*)d_in[0],   // input_seq
        (const float*)d_in[1],   // enc_Wih
        (const float*)d_in[2],   // enc_Whh
        (const float*)d_in[3],   // enc_bih
        (const float*)d_in[4],   // enc_bhh
        (const float*)d_in[5],   // dec_Wih
        (const float*)d_in[6],   // dec_Whh
        (const float*)d_in[7],   // dec_bih
        (const float*)d_in[8],   // dec_bhh
        (const float*)d_in[9],   // fc_W
        (const float*)d_in[10],  // fc_b
        (float*)d_out,
        (unsigned*)d_ws);
}

// Round 2
// 8679.597 us; speedup vs baseline: 1.1431x; 1.1431x over previous
//
#include <hip/hip_runtime.h>

// Seq2Seq LSTM H=128: enc 8192 + dec 4096 strictly sequential steps.
// Single block, one CU, 512 threads (8 waves). ONE barrier per step.
//
// R10. Prober findings (R9): sustained core clock ~1630 MHz during
// back-to-back dispatches (tail-encoded 815 us = MHz/2); T_main was
// 9106 us in BOTH R8 (255 heater CUs) and R9 (idle chip) => DPM state
// is activity-invariant here; heaters/prober all deleted. First
// dispatch of a cold pass runs ~4x slow (idle-clock ramp) - ignore.
// Budget: 741 ns/step = ~1208 cyc @ 1.63 GHz.
//
// R10 changes (cycle cuts, same structure):
//  * grid 2 -> 1: prober removed (recovers its 815 us tail).
//  * pk_fma_s: h-broadcast pair passed as SGPR-PAIR operand ("s"
//    constraint) to v_pk_fma_f32 - kills 16 v_mov/lane/step that
//    materialized the uniform pair into VGPRs (pair packing becomes
//    SALU s_mov, co-issues off the VALU pipe).
//  * REDUCE: 8-partial sum tree-reassociated (depth 8 -> 3) to
//    shorten the serial post-barrier chain.
//  * encoder: per-step hbuf store dropped (only final h needed;
//    stored once after the loop). Decoder still stores every step
//    (out[st-2] reads 2-step-stale hbuf).

#define H      128
#define ENC_T  8192
#define DEC_T  4096
#define NT     512
#define NBLK   1
#define PSLICE 648          // floats per slice stride; idx = 5u+g <= 638

typedef float v2f __attribute__((ext_vector_type(2)));

__device__ __forceinline__ v2f pk_fma_s(v2f a, v2f b_sgpr, v2f c) {
    v2f d;   // b is wave-uniform: read as 64-bit scalar operand (s-pair)
    asm("v_pk_fma_f32 %0, %1, %2, %3" : "=v"(d) : "v"(a), "s"(b_sgpr), "v"(c));
    return d;
}
__device__ __forceinline__ v2f pk_fma(v2f a, v2f b, v2f c) {
    v2f d;
    asm("v_pk_fma_f32 %0, %1, %2, %3" : "=v"(d) : "v"(a), "v"(b), "v"(c));
    return d;
}
__device__ __forceinline__ float sigm(float x) {
    return __builtin_amdgcn_rcpf(1.0f + __expf(-x));   // exact at +-inf
}
__device__ __forceinline__ float tanhfast(float x) {
    return 1.0f - 2.0f * __builtin_amdgcn_rcpf(1.0f + __expf(2.0f * x));
}
__device__ __forceinline__ float rdlane(float v, int l) {
    return __int_as_float(__builtin_amdgcn_readlane(__float_as_int(v), l));
}
template <int CTRL>
__device__ __forceinline__ float qperm(float v) {      // DPP quad_perm, VALU-speed
    return __int_as_float(
        __builtin_amdgcn_mov_dpp(__float_as_int(v), CTRL, 0xf, 0xf, true));
}

__global__ __launch_bounds__(NT, 2)
void seq2seq_lstm(const float* __restrict__ input_seq,
                  const float* __restrict__ enc_Wih,
                  const float* __restrict__ enc_Whh,
                  const float* __restrict__ enc_bih,
                  const float* __restrict__ enc_bhh,
                  const float* __restrict__ dec_Wih,
                  const float* __restrict__ dec_Whh,
                  const float* __restrict__ dec_bih,
                  const float* __restrict__ dec_bhh,
                  const float* __restrict__ fc_W,
                  const float* __restrict__ fc_b,
                  float* __restrict__ out,
                  unsigned* __restrict__ wsflag)
{
    (void)wsflag;
    __shared__ __align__(16) float xin[ENC_T];          // 32 KB
    __shared__ __align__(16) float hbuf[2][H];          // h history (off-path)
    __shared__ __align__(16) float part[2][8 * PSLICE]; // dbl-buffered partials

    const int t    = threadIdx.x;      // 0..511
    const int lane = t & 63;
    const int wv   = t >> 6;           // wave 0..7, j-slice [16wv,16wv+16)
    const int jb   = 16 * wv;
    const int qq   = lane >> 2;        // reduce role: unit-in-slice 0..15
    const int g    = lane & 3;         // gate 0=i 1=f 2=g 3=o
    const int myu  = jb + qq;          // my unit (global)
    const int myrow = g * H + myu;     // my gate row
    const int prd  = 5 * myu + g;      // partial read idx within a slice
    const int pwb  = wv * PSLICE + 5 * lane;   // partial write base

    {   // stage input sequence
        const float4* s = (const float4*)input_seq;
        float4* d = (float4*)xin;
        for (int i = t; i < ENC_T / 4; i += NT) d[i] = s[i];
    }

    // matvec weights as j-pairs: w2[s][jj] = Whh[(64s+lane)][jb+2jj, jb+2jj+1]
    v2f w2[8][8];
#pragma unroll
    for (int s = 0; s < 8; ++s) {
        const v2f* Wr = (const v2f*)(enc_Whh + (64 * s + lane) * H + jb);
#pragma unroll
        for (int jj = 0; jj < 8; ++jj) w2[s][jj] = Wr[jj];
    }
    float bias_r = enc_bih[myrow] + enc_bhh[myrow];
    float wih_r  = enc_Wih[myrow];

    float cst = 0.f;      // cell state of unit myu (replicated per quad)
    float hn  = 0.f;      // h of unit myu (replicated per quad)
    __syncthreads();

    // h[jb+2jj+c] lives in quad 2jj+c of this wave -> g==3 lane 8jj+4c+3
#define MATVEC(PB)                                                          \
    {                                                                       \
        v2f acc2[8];                                                        \
        _Pragma("unroll") for (int s = 0; s < 8; ++s)                       \
            acc2[s] = (v2f){0.f, 0.f};                                      \
        _Pragma("unroll") for (int jj = 0; jj < 8; ++jj) {                  \
            const float se = rdlane(hn, 8 * jj + 3);                        \
            const float so = rdlane(hn, 8 * jj + 7);                        \
            const v2f hp = {se, so};                                        \
            _Pragma("unroll") for (int s = 0; s < 8; ++s)                   \
                acc2[s] = pk_fma_s(w2[s][jj], hp, acc2[s]);                 \
        }                                                                   \
        /* row 64s+lane -> idx 5*lane + 320*(s&1) + (s>>1), stride-5 */     \
        float* pb_ = &part[PB][pwb];                                        \
        pb_[0]   = acc2[0].x + acc2[0].y; pb_[320] = acc2[1].x + acc2[1].y; \
        pb_[1]   = acc2[2].x + acc2[2].y; pb_[321] = acc2[3].x + acc2[3].y; \
        pb_[2]   = acc2[4].x + acc2[4].y; pb_[322] = acc2[5].x + acc2[5].y; \
        pb_[3]   = acc2[6].x + acc2[6].y; pb_[323] = acc2[7].x + acc2[7].y; \
    }

    // STH: 1 -> store h to hbuf[PB] (decoder needs 2-step-stale h)
#define REDUCE_UPDATE(PB, ABASE, STH)                                       \
    {                                                                       \
        const float p0 = part[PB][0 * PSLICE + prd];                        \
        const float p1 = part[PB][1 * PSLICE + prd];                        \
        const float p2 = part[PB][2 * PSLICE + prd];                        \
        const float p3 = part[PB][3 * PSLICE + prd];                        \
        const float p4 = part[PB][4 * PSLICE + prd];                        \
        const float p5 = part[PB][5 * PSLICE + prd];                        \
        const float p6 = part[PB][6 * PSLICE + prd];                        \
        const float p7 = part[PB][7 * PSLICE + prd];                        \
        const float a = (ABASE) + (((p0 + p1) + (p2 + p3)) +                \
                                   ((p4 + p5) + (p6 + p7)));                \
        const float v = (g == 2) ? tanhfast(a) : sigm(a);                   \
        const float vi = qperm<0x00>(v);   /* quad lane 0 */                \
        const float vf = qperm<0x55>(v);   /* quad lane 1 */                \
        const float vg = qperm<0xAA>(v);   /* quad lane 2 */                \
        const float vo = qperm<0xFF>(v);   /* quad lane 3 */                \
        cst = fmaf(vf, cst, vi * vg);                                       \
        hn  = vo * tanhfast(cst);                                           \
        if (STH && g == 3) hbuf[PB][myu] = hn;                              \
    }

    // ---------------- encoder: 8192 steps, ONE barrier each ----------------
    for (int st = 0; st < ENC_T; ++st) {
        const int pb = st & 1;
        MATVEC(pb);
        const float x = xin[st];
        __syncthreads();
        REDUCE_UPDATE(pb, fmaf(wih_r, x, bias_r), 0);
    }
    if (g == 3) hbuf[1][myu] = hn;         // final encoder h, once

    // ---------------- decoder setup: fold fc into Whh ----------------
    const float fcb = fc_b[0];
    const float fwl = fc_W[lane];
    const float fwh = fc_W[64 + lane];
#pragma unroll
    for (int s = 0; s < 8; ++s) {
        const int r = 64 * s + lane;
        const float vi = dec_Wih[r];
        const v2f vip = {vi, vi};
        const v2f* Wr = (const v2f*)(dec_Whh + r * H + jb);
        const v2f* Fr = (const v2f*)(fc_W + jb);
#pragma unroll
        for (int jj = 0; jj < 8; ++jj)
            w2[s][jj] = pk_fma(vip, Fr[jj], Wr[jj]);   // W' = Whh + wih (x) fcW
    }
    wih_r  = dec_Wih[myrow];
    bias_r = dec_bih[myrow] + dec_bhh[myrow] + wih_r * fcb;
    __syncthreads();                       // h_enc visible in hbuf[1]
    float q0;
    {
        float p = fmaf(fwl, hbuf[1][lane], fwh * hbuf[1][64 + lane]);
        p += qperm<0xB1>(p);               // xor 1
        p += qperm<0x4E>(p);               // xor 2
#pragma unroll
        for (int m = 32; m >= 4; m >>= 1) p += __shfl_xor(p, m, 64);
        q0 = p + fcb;
    }
    float cb = bias_r - wih_r * q0;        // step-0 correction (y0 = 0)

    // ---------------- decoder: 4096 steps ----------------
    for (int st = 0; st < DEC_T; ++st) {
        const int pb = st & 1;
        MATVEC(pb);
        if (wv == 7 && st >= 2) {          // out[st-2] from 2-step-stale hbuf
            float p = fmaf(fwl, hbuf[pb][lane], fwh * hbuf[pb][64 + lane]);
            p += qperm<0xB1>(p);
            p += qperm<0x4E>(p);
#pragma unroll
            for (int m = 32; m >= 4; m >>= 1) p += __shfl_xor(p, m, 64);
            if (lane == 0) out[st - 2] = p + fcb;
        }
        __syncthreads();
        REDUCE_UPDATE(pb, cb, 1);
        cb = bias_r;
    }

    // tail outputs for steps DEC_T-2 (hbuf[0]) and DEC_T-1 (hbuf[1])
    __syncthreads();
    if (wv == 7) {
        float p0 = fmaf(fwl, hbuf[0][lane], fwh * hbuf[0][64 + lane]);
        float p1 = fmaf(fwl, hbuf[1][lane], fwh * hbuf[1][64 + lane]);
#pragma unroll
        for (int m = 32; m >= 1; m >>= 1) {
            p0 += __shfl_xor(p0, m, 64);
            p1 += __shfl_xor(p1, m, 64);
        }
        if (lane == 0) {
            out[DEC_T - 2] = p0 + fcb;
            out[DEC_T - 1] = p1 + fcb;
        }
    }
}

extern "C" void kernel_launch(void* const* d_in, const int* in_sizes, int n_in,
                              void* d_out, int out_size, void* d_ws, size_t ws_size,
                              hipStream_t stream)
{
    (void)in_sizes; (void)n_in; (void)ws_size; (void)out_size;
    seq2seq_lstm<<<NBLK, NT, 0, stream>>>(
        (const float*)d_in[0],   // input_seq
        (const float*)d_in[1],   // enc_Wih
        (const float*)d_in[2],   // enc_Whh
        (const float*)d_in[3],   // enc_bih
        (const float*)d_in[4],   // enc_bhh
        (const float*)d_in[5],   // dec_Wih
        (const float*)d_in[6],   // dec_Whh
        (const float*)d_in[7],   // dec_bih
        (const float*)d_in[8],   // dec_bhh
        (const float*)d_in[9],   // fc_W
        (const float*)d_in[10],  // fc_b
        (float*)d_out,
        (unsigned*)d_ws);
}

// Round 3
// 8124.071 us; speedup vs baseline: 1.2212x; 1.0684x over previous
//
#include <hip/hip_runtime.h>

// Seq2Seq LSTM H=128: enc 8192 + dec 4096 strictly sequential steps.
// Single block, one CU, 512 threads (8 waves). ONE barrier per step.
//
// Model (R10, @1.63GHz sustained): 1144 cyc/step/SIMD = 512 FMA-issue
// floor + ~630 overhead (readlane 64, LDS ops ~100, adds 36, transc 80,
// barrier ~75, exposed post-barrier ds_read+chain latency ~150-200).
//
// R11 changes (overhead cuts; same arithmetic precision):
//  * Partial exchange repacked: partial for row r from wave wv now at
//    flat = 8*prd(r) + (wv ^ ((prd>>2)&7)), prd = 5*(r&127) + (r>>7).
//    Each row's 8 partials = one contiguous 32B block -> reader does
//    2x ds_read_b128 (was 8x b32). Per-lane half-order p=(prd>>2)&1
//    spreads starts over all 8 16B windows (prd%8 uniform) = bank-
//    optimal. Writer still 8x b32; XOR col keeps writer banks ~2-way.
//    Sum order permuted per lane (rounding-level change only).
//  * Decoder fc-output moved into the post-barrier latency shadow:
//    wave 7 computes out[st-1] from hbuf[(st-1)&1] (stable: this
//    step's REDUCE writes the other parity) while its part-reads are
//    in flight. Removes the pre-barrier straggler. Tail = out[4095].
//  * Loops explicitly unrolled x2 (parity literal).

#define H      128
#define ENC_T  8192
#define DEC_T  4096
#define NT     512
#define NBLK   1
#define PBUF   5120         // floats per partial buffer: 8*638+7 < 5120

typedef float v2f __attribute__((ext_vector_type(2)));

__device__ __forceinline__ v2f pk_fma_s(v2f a, v2f b_sgpr, v2f c) {
    v2f d;   // b is wave-uniform: read as 64-bit scalar operand (s-pair)
    asm("v_pk_fma_f32 %0, %1, %2, %3" : "=v"(d) : "v"(a), "s"(b_sgpr), "v"(c));
    return d;
}
__device__ __forceinline__ v2f pk_fma(v2f a, v2f b, v2f c) {
    v2f d;
    asm("v_pk_fma_f32 %0, %1, %2, %3" : "=v"(d) : "v"(a), "v"(b), "v"(c));
    return d;
}
__device__ __forceinline__ float sigm(float x) {
    return __builtin_amdgcn_rcpf(1.0f + __expf(-x));   // exact at +-inf
}
__device__ __forceinline__ float tanhfast(float x) {
    return 1.0f - 2.0f * __builtin_amdgcn_rcpf(1.0f + __expf(2.0f * x));
}
__device__ __forceinline__ float rdlane(float v, int l) {
    return __int_as_float(__builtin_amdgcn_readlane(__float_as_int(v), l));
}
template <int CTRL>
__device__ __forceinline__ float qperm(float v) {      // DPP quad_perm, VALU-speed
    return __int_as_float(
        __builtin_amdgcn_mov_dpp(__float_as_int(v), CTRL, 0xf, 0xf, true));
}

__global__ __launch_bounds__(NT, 2)
void seq2seq_lstm(const float* __restrict__ input_seq,
                  const float* __restrict__ enc_Wih,
                  const float* __restrict__ enc_Whh,
                  const float* __restrict__ enc_bih,
                  const float* __restrict__ enc_bhh,
                  const float* __restrict__ dec_Wih,
                  const float* __restrict__ dec_Whh,
                  const float* __restrict__ dec_bih,
                  const float* __restrict__ dec_bhh,
                  const float* __restrict__ fc_W,
                  const float* __restrict__ fc_b,
                  float* __restrict__ out,
                  unsigned* __restrict__ wsflag)
{
    (void)wsflag;
    __shared__ __align__(16) float xin[ENC_T];          // 32 KB
    __shared__ __align__(16) float hbuf[2][H];          // h history (off-path)
    __shared__ __align__(16) float part[2][PBUF];       // dbl-buffered partials

    const int t    = threadIdx.x;      // 0..511
    const int lane = t & 63;
    const int wv   = t >> 6;           // wave 0..7, j-slice [16wv,16wv+16)
    const int jb   = 16 * wv;
    const int qq   = lane >> 2;        // reduce role: unit-in-slice 0..15
    const int g    = lane & 3;         // gate 0=i 1=f 2=g 3=o
    const int myu  = jb + qq;          // my unit (global)
    const int myrow = g * H + myu;     // my gate row

    // reader addresses: row's 8 partials contiguous at 8*prd
    const int prd = 5 * myu + g;
    const int pA  = (prd >> 2) & 1;                 // half-order spread
    const int rA  = 8 * prd + 4 * pA;
    const int rB  = 8 * prd + 4 - 4 * pA;
    // writer addresses: value for row 64s+lane -> block 8*pw, col wv^swz
    int widx[8];
    {
        const int SOFF[8] = {0, 320, 1, 321, 2, 322, 3, 323};
#pragma unroll
        for (int s = 0; s < 8; ++s) {
            const int pw = 5 * lane + SOFF[s];
            widx[s] = 8 * pw + (wv ^ ((pw >> 2) & 7));
        }
    }

    {   // stage input sequence
        const float4* s = (const float4*)input_seq;
        float4* d = (float4*)xin;
        for (int i = t; i < ENC_T / 4; i += NT) d[i] = s[i];
    }

    // matvec weights as j-pairs: w2[s][jj] = Whh[(64s+lane)][jb+2jj, jb+2jj+1]
    v2f w2[8][8];
#pragma unroll
    for (int s = 0; s < 8; ++s) {
        const v2f* Wr = (const v2f*)(enc_Whh + (64 * s + lane) * H + jb);
#pragma unroll
        for (int jj = 0; jj < 8; ++jj) w2[s][jj] = Wr[jj];
    }
    float bias_r = enc_bih[myrow] + enc_bhh[myrow];
    float wih_r  = enc_Wih[myrow];

    float cst = 0.f;      // cell state of unit myu (replicated per quad)
    float hn  = 0.f;      // h of unit myu (replicated per quad)
    __syncthreads();

    // h[jb+2jj+c] lives in quad 2jj+c of this wave -> g==3 lane 8jj+4c+3
#define MATVEC(PB)                                                          \
    {                                                                       \
        v2f acc2[8];                                                        \
        _Pragma("unroll") for (int s = 0; s < 8; ++s)                       \
            acc2[s] = (v2f){0.f, 0.f};                                      \
        _Pragma("unroll") for (int jj = 0; jj < 8; ++jj) {                  \
            const float se = rdlane(hn, 8 * jj + 3);                        \
            const float so = rdlane(hn, 8 * jj + 7);                        \
            const v2f hp = {se, so};                                        \
            _Pragma("unroll") for (int s = 0; s < 8; ++s)                   \
                acc2[s] = pk_fma_s(w2[s][jj], hp, acc2[s]);                 \
        }                                                                   \
        float* pb_ = &part[PB][0];                                          \
        _Pragma("unroll") for (int s = 0; s < 8; ++s)                       \
            pb_[widx[s]] = acc2[s].x + acc2[s].y;                           \
    }

#define RED_LOAD(PB)                                                        \
    const float4 a4_ = *(const float4*)&part[PB][rA];                       \
    const float4 b4_ = *(const float4*)&part[PB][rB];

    // STH: 1 -> store h to hbuf[PB] (decoder out reads stale hbuf)
#define RED_FIN(PB, ABASE, STH)                                             \
    {                                                                       \
        const float a = (ABASE) +                                           \
            (((a4_.x + a4_.y) + (a4_.z + a4_.w)) +                          \
             ((b4_.x + b4_.y) + (b4_.z + b4_.w)));                          \
        const float v = (g == 2) ? tanhfast(a) : sigm(a);                   \
        const float vi = qperm<0x00>(v);   /* quad lane 0 */                \
        const float vf = qperm<0x55>(v);   /* quad lane 1 */                \
        const float vg = qperm<0xAA>(v);   /* quad lane 2 */                \
        const float vo = qperm<0xFF>(v);   /* quad lane 3 */                \
        cst = fmaf(vf, cst, vi * vg);                                       \
        hn  = vo * tanhfast(cst);                                           \
        if (STH && g == 3) hbuf[PB][myu] = hn;                              \
    }

    // post-barrier fc output: out[ST-1] from hbuf[HB] (= h after step ST-1;
    // stable: this step's REDUCE writes hbuf[1-HB]). Runs in wave 7's
    // part-read latency shadow.
#define OUTBLK(ST, HB)                                                      \
    if (wv == 7 && (ST) >= 1) {                                             \
        float p = fmaf(fwl, hbuf[HB][lane], fwh * hbuf[HB][64 + lane]);     \
        p += qperm<0xB1>(p);               /* xor 1 */                      \
        p += qperm<0x4E>(p);               /* xor 2 */                      \
        _Pragma("unroll") for (int m = 32; m >= 4; m >>= 1)                 \
            p += __shfl_xor(p, m, 64);                                      \
        if (lane == 0) out[(ST) - 1] = p + fcb;                             \
    }

    // ---------------- encoder: 8192 steps, ONE barrier each ----------------
    for (int st = 0; st < ENC_T; st += 2) {
        {
            MATVEC(0);
            const float x = xin[st];
            __syncthreads();
            RED_LOAD(0);
            RED_FIN(0, fmaf(wih_r, x, bias_r), 0);
        }
        {
            MATVEC(1);
            const float x = xin[st + 1];
            __syncthreads();
            RED_LOAD(1);
            RED_FIN(1, fmaf(wih_r, x, bias_r), 0);
        }
    }
    if (g == 3) hbuf[1][myu] = hn;         // final encoder h, once

    // ---------------- decoder setup: fold fc into Whh ----------------
    const float fcb = fc_b[0];
    const float fwl = fc_W[lane];
    const float fwh = fc_W[64 + lane];
#pragma unroll
    for (int s = 0; s < 8; ++s) {
        const int r = 64 * s + lane;
        const float vi = dec_Wih[r];
        const v2f vip = {vi, vi};
        const v2f* Wr = (const v2f*)(dec_Whh + r * H + jb);
        const v2f* Fr = (const v2f*)(fc_W + jb);
#pragma unroll
        for (int jj = 0; jj < 8; ++jj)
            w2[s][jj] = pk_fma(vip, Fr[jj], Wr[jj]);   // W' = Whh + wih (x) fcW
    }
    wih_r  = dec_Wih[myrow];
    bias_r = dec_bih[myrow] + dec_bhh[myrow] + wih_r * fcb;
    __syncthreads();                       // h_enc visible in hbuf[1]
    float q0;
    {
        float p = fmaf(fwl, hbuf[1][lane], fwh * hbuf[1][64 + lane]);
        p += qperm<0xB1>(p);               // xor 1
        p += qperm<0x4E>(p);               // xor 2
#pragma unroll
        for (int m = 32; m >= 4; m >>= 1) p += __shfl_xor(p, m, 64);
        q0 = p + fcb;
    }
    float cb = bias_r - wih_r * q0;        // step-0 correction (y0 = 0)

    // ---------------- decoder: 4096 steps ----------------
    for (int st = 0; st < DEC_T; st += 2) {
        {   // even step ST=st: out[st-1] from hbuf[1] (odd-parity h)
            MATVEC(0);
            __syncthreads();
            RED_LOAD(0);
            OUTBLK(st, 1);
            RED_FIN(0, cb, 1);
            cb = bias_r;
        }
        {   // odd step ST=st+1: out[st] from hbuf[0]
            MATVEC(1);
            __syncthreads();
            RED_LOAD(1);
            OUTBLK(st + 1, 0);
            RED_FIN(1, cb, 1);
        }
    }

    // tail: out[DEC_T-1] from hbuf[1] (h after final step, parity 1)
    __syncthreads();
    if (wv == 7) {
        float p = fmaf(fwl, hbuf[1][lane], fwh * hbuf[1][64 + lane]);
        p += qperm<0xB1>(p);
        p += qperm<0x4E>(p);
#pragma unroll
        for (int m = 32; m >= 4; m >>= 1) p += __shfl_xor(p, m, 64);
        if (lane == 0) out[DEC_T - 1] = p + fcb;
    }
}

extern "C" void kernel_launch(void* const* d_in, const int* in_sizes, int n_in,
                              void* d_out, int out_size, void* d_ws, size_t ws_size,
                              hipStream_t stream)
{
    (void)in_sizes; (void)n_in; (void)ws_size; (void)out_size;
    seq2seq_lstm<<<NBLK, NT, 0, stream>>>(
        (const float*)d_in[0],   // input_seq
        (const float*)d_in[1],   // enc_Wih
        (const float*)d_in[2],   // enc_Whh
        (const float*)d_in[3],   // enc_bih
        (const float*)d_in[4],   // enc_bhh
        (const float*)d_in[5],   // dec_Wih
        (const float*)d_in[6],   // dec_Whh
        (const float*)d_in[7],   // dec_bih
        (const float*)d_in[8],   // dec_bhh
        (const float*)d_in[9],   // fc_W
        (const float*)d_in[10],  // fc_b
        (float*)d_out,
        (unsigned*)d_ws);
}